// Round 7
// baseline (372.968 us; speedup 1.0000x reference)
//
#include <hip/hip_runtime.h>

// HebbianConv2d: y = conv2d(x, w/||w||) + bias ; delta_w = cr @ unfold(x) - (sum cr)*w
// where r = softmax_o(y), cr = r^2 / sum_{b,h,w}(r)
//
// R10 -> R11: merge the mode branch into ONE passAB kernel (runtime
// grid-uniform branch on *mode), deleting the 1016-block template stub
// dispatch. Evidence: residual (total - passAB) was 148 us with R9's merged
// kernel vs 177-181 us with the two-dispatch form -> ~25-30 us/dispatch of
// launch overhead. R10's swizzle kept (FETCH 113->38 MB, confirmed T1
// mechanism; dur-neutral -> not fetch-bound). Everything else identical to
// R10's verified single-buffer structure.

typedef unsigned short ushort_t;
typedef __attribute__((ext_vector_type(8)))  short  short8v;
typedef __attribute__((ext_vector_type(4)))  float  float4v;
typedef __attribute__((ext_vector_type(16))) float  float16v;

struct __attribute__((packed, aligned(4))) f4a { float x,y,z,w; };
struct __attribute__((packed, aligned(2))) u2a { ushort_t x,y; };

#define BATCH 16
#define CIN   16
#define H     256
#define W     256
#define HW    (H*W)
#define OCH   32
#define HO    254
#define WO    254
#define LPOS  (HO*WO)            // 64516
#define YELEMS (BATCH*OCH*LPOS)  // 33032192
#define KFEAT 144
#define NROWS (BATCH*HO)         // 4064
#define NCHUNK (NROWS*8)         // 32512 chunks of 32 padded positions
#define GRIDA 1016               // fused blocks: 1016*4 waves * 8 chunks = 32512 exact
#define NSLAB GRIDA              // one partial slab per block
#define NGRP  8
#define SLABS_PER_GRP 127        // 1016/8

#define TCOLS 36                 // x-tile floats per row (48 rows = 16c x 3ii)

// ws layout in floats
#define WS_RSUM 0        // 32
#define WS_R2   32       // 32
#define WS_ACC  64       // 4608: fallback atomic accumulator
#define WS_MODE 4672     // 1 int: 0=bf16 inputs, 1=fp32 inputs
#define WS_WNB  4680     // 4608 ushorts (2304 floats): wnb[ij][c][och] bf16
#define WS_PART 8192     // NSLAB*4608 floats
#define WS_PART2 (8192 + NSLAB*4608)          // NGRP*4608 floats
#define WS_NEED ((size_t)(WS_PART2 + NGRP*4608)*4)   // ~18.9 MB

__device__ __forceinline__ float bf2f(ushort_t u){
  union{unsigned u; float f;} c; c.u = ((unsigned)u) << 16; return c.f;
}
__device__ __forceinline__ ushort_t f2bf(float f){
  union{float f; unsigned u;} c; c.f = f;
  unsigned x = c.u;
  return (ushort_t)((x + 0x7fffu + ((x >> 16) & 1u)) >> 16);   // RNE
}
__device__ __forceinline__ unsigned as_u(float f){
  union{float f; unsigned u;} c; c.f = f; return c.u;
}
__device__ __forceinline__ void gload_lds16(const float* g, void* l){
  __builtin_amdgcn_global_load_lds(
      (const __attribute__((address_space(1))) void*)g,
      (__attribute__((address_space(3))) void*)l, 16, 0, 0);
}

// prep (includes mode detect): bf16 N(0,1): exponent <= 0x81. fp32 storage:
// even ushorts are mantissa halves -> ~45% have exp >= 0x8C. Scan 32 KB.
__global__ __launch_bounds__(256) void hebb_prep(const ushort_t* __restrict__ x,
                                                 const ushort_t* __restrict__ w,
                                                 int* __restrict__ mode,
                                                 float* __restrict__ ws){
  int tid = threadIdx.x;
  int bad = 0;
  for (int i = tid; i < 16384; i += 256){
    unsigned e = ((unsigned)x[i] >> 7) & 0xFFu;
    bad |= (e >= 0x8Cu) ? 1 : 0;
  }
  unsigned long long m = __ballot(bad);
  __shared__ unsigned long long sm[4];
  __shared__ int mode_s;
  int wv = tid >> 6;
  if ((tid & 63) == 0) sm[wv] = m;
  __syncthreads();
  if (tid == 0){
    int md = ((sm[0] | sm[1] | sm[2] | sm[3]) != 0ULL) ? 1 : 0;
    *mode = md; mode_s = md;
  }
  __syncthreads();
  const int fp32 = mode_s;
  const float* wf = (const float*)w;
  __shared__ float inv_s[OCH];
  if (tid < OCH){
    float s = 0.f;
    for (int k = 0; k < KFEAT; k++){
      float v = fp32 ? wf[tid*KFEAT + k] : bf2f(w[tid*KFEAT + k]);
      s += v*v;
    }
    float nrm = sqrtf(s);
    inv_s[tid] = (nrm == 0.f) ? 1.f : (1.f/nrm);
  }
  __syncthreads();
  ushort_t* wnb = (ushort_t*)(ws + WS_WNB);
  for (int i = tid; i < 4608; i += 256){
    // i = (ij*16 + c)*32 + o ; k_full = c*9 + ij
    int o = i & 31, rest = i >> 5;
    int ij = rest >> 4, c = rest & 15;
    int k = c*9 + ij;
    float v = fp32 ? wf[o*KFEAT + k] : bf2f(w[o*KFEAT + k]);
    wnb[i] = f2bf(v * inv_s[o]);
    ws[WS_ACC + i] = 0.f;
  }
  if (tid < 64) ws[WS_RSUM + tid] = 0.f;
}

// Fused: MFMA conv + softmax + reductions + y, then hebb r^2 @ x via per-wave
// LDS transpose of r^2 (C-layout -> 16x16x32 A-frag layout). x comes from a
// per-wave LDS tile staged once per chunk (fp32 mode). Single kernel,
// runtime grid-uniform branch on mode.
__global__ __launch_bounds__(256, 2) void hebb_passAB(
    const void* __restrict__ xv_, const void* __restrict__ bias_,
    const int* __restrict__ mode, const float* __restrict__ ws,
    float* __restrict__ rsum_g, float* __restrict__ r2sum_g,
    void* __restrict__ yout_, float* __restrict__ partial, int do_hebb){
  const int fp32 = *mode;
  __shared__ __align__(16) float xtile[4][1792];     // 28672 B; redp alias post-loop
  __shared__ __align__(16) ushort_t r2t[4][32*40];   // per-wave r^2 tile, stride 40
  __shared__ float red_s[64];
  float* redp = &xtile[0][0];                        // 4608 floats, used after loop
  int tid = threadIdx.x;
  if (tid < 64) red_s[tid] = 0.f;
  __syncthreads();
  int wave = tid >> 6, lane = tid & 63;
  int pos = lane & 31, half = lane >> 5;
  int quad = lane >> 4, l16 = lane & 15;

  // XCD swizzle (T1): default dispatch round-robins bids over 8 XCDs; remap so
  // each XCD owns a contiguous block range -> ho-adjacent rows share its L2.
  int bid = (int)blockIdx.x;
  int swz = (bid & 7)*127 + (bid >> 3);              // bijective, 1016 = 8*127

  // conv A-fragments: wnb[ij][c][och]; lane: m = och = lane&31, k = half*8+i
  const ushort_t* wnb = (const ushort_t*)(ws + WS_WNB);
  short8v wa[9];
  #pragma unroll
  for (int ij = 0; ij < 9; ij++){
    union{ushort_t s[8]; short8v v;} pk;
    #pragma unroll
    for (int i = 0; i < 8; i++)
      pk.s[i] = wnb[(ij*16 + half*8 + i)*32 + pos];
    wa[ij] = pk.v;
  }
  // bias per C-reg row: och_r = (r&3)+8*(r>>2)+4*half
  float bv[16];
  #pragma unroll
  for (int r = 0; r < 16; r++){
    int och = (r&3) + 8*(r>>2) + 4*half;
    bv[r] = fp32 ? ((const float*)bias_)[och] : bf2f(((const ushort_t*)bias_)[och]);
  }
  float rsA[16];
  #pragma unroll
  for (int r = 0; r < 16; r++) rsA[r] = 0.f;
  float r2B0 = 0.f, r2B1 = 0.f;          // Sum r^2 for och=l16 and och=16+l16

  // staging slot map (fp32): slot = i*64+lane -> tile row r=slot/9 (c*3+ii),
  // within-row 16B quarter q=slot%9. 7 instrs x 64 lanes covers 48x36 floats.
  int goff[7], qcol[7];
  #pragma unroll
  for (int i = 0; i < 7; i++){
    int slot = i*64 + lane; slot = (slot > 431) ? 431 : slot;
    int rr = slot/9, q = slot - 9*rr;
    int c = rr/3, ii = rr - 3*c;
    goff[i] = c*HW + ii*W;
    qcol[i] = q*4;
  }

  float4v hacc[18];
  #pragma unroll
  for (int i = 0; i < 18; i++) hacc[i] = (float4v){0.f,0.f,0.f,0.f};

  ushort_t* t2 = r2t[wave];
  float* tw = &xtile[wave][0];

  for (int cc0 = swz*4 + wave; cc0 < NCHUNK; cc0 += GRIDA*4){
    int cc = __builtin_amdgcn_readfirstlane(cc0);
    int row = cc >> 3, sub = cc & 7;
    int b = row / HO, ho = row - b*HO;
    int wo0 = sub << 5;
    int wo = wo0 + pos;                 // 254,255 dead on sub==7
    int tail = (sub == 7);

    float16v av;
    #pragma unroll
    for (int r = 0; r < 16; r++) av[r] = bv[r];   // C init = bias

    if (fp32){
      // ---- stage x tile: rows (c*3+ii), cols wo0..wo0+35 (clamped) ----
      const float* xb = (const float*)xv_ + (size_t)b*(CIN*HW) + (size_t)ho*W;
      #pragma unroll
      for (int i = 0; i < 7; i++){
        int col = wo0 + qcol[i]; col = (col > 252) ? 252 : col;  // stay in-row
        gload_lds16(xb + goff[i] + col, (char*)tw + i*1024);
      }
      asm volatile("s_waitcnt vmcnt(0)" ::: "memory");

      // ---- conv: operands from tile (chunk-invariant LDS addresses) ----
      #pragma unroll
      for (int ij = 0; ij < 9; ij++){
        const int ii = ij/3, jj = ij - 3*ii;
        unsigned g[8];
        #pragma unroll
        for (int i2 = 0; i2 < 8; i2++)
          g[i2] = as_u(tw[((half*8 + i2)*3 + ii)*TCOLS + pos + jj]) + 0x8000u;
        union{unsigned u[4]; short8v v;} pk;
        pk.u[0] = __builtin_amdgcn_perm(g[1], g[0], 0x07060302u);  // rnd-half-up
        pk.u[1] = __builtin_amdgcn_perm(g[3], g[2], 0x07060302u);
        pk.u[2] = __builtin_amdgcn_perm(g[5], g[4], 0x07060302u);
        pk.u[3] = __builtin_amdgcn_perm(g[7], g[6], 0x07060302u);
        av = __builtin_amdgcn_mfma_f32_32x32x16_bf16(wa[ij], pk.v, av, 0, 0, 0);
      }
    } else {
      // bf16-mode: original clamped scalar path
      #pragma unroll
      for (int ij = 0; ij < 9; ij++){
        const int ii = ij/3, jj = ij - 3*ii;
        int wcol = wo + jj; wcol = (wcol < 256) ? wcol : 255;   // clamp: no OOB
        size_t a0 = (size_t)b*(CIN*HW) + (size_t)(half*8)*HW + (size_t)(ho+ii)*W + wcol;
        const ushort_t* xp = (const ushort_t*)xv_;
        union{ushort_t s[8]; short8v v;} pk;
        #pragma unroll
        for (int i2 = 0; i2 < 8; i2++)
          pk.s[i2] = xp[a0 + (size_t)i2*HW];
        av = __builtin_amdgcn_mfma_f32_32x32x16_bf16(wa[ij], pk.v, av, 0, 0, 0);
      }
    }

    // y store (C/D: col=lane&31=pos, row=(r&3)+8*(r>>2)+4*half=och)
    int valid = (wo < WO) ? 1 : 0;
    if (valid){
      size_t yb = (size_t)b*(OCH*(size_t)LPOS) + (size_t)(half*4)*LPOS
                + (size_t)ho*WO + wo;
      #pragma unroll
      for (int r = 0; r < 16; r++){
        size_t yi = yb + (size_t)(((r&3) + 8*(r>>2)))*LPOS;
        if (fp32) ((float*)yout_)[yi] = av[r];
        else      ((ushort_t*)yout_)[yi] = f2bf(av[r]);
      }
    }

    // softmax over och (16 local + partner half via shfl_xor 32)
    float m = -3.0e38f;
    #pragma unroll
    for (int r = 0; r < 16; r++) m = fmaxf(m, av[r]);
    m = fmaxf(m, __shfl_xor(m, 32));
    float s = 0.f;
    #pragma unroll
    for (int r = 0; r < 16; r++){ float e = __expf(av[r] - m); av[r] = e; s += e; }
    s += __shfl_xor(s, 32);
    float inv = valid ? (1.f/s) : 0.f;

    // r^2 -> per-wave LDS tile [och][pos], stride 40 elems (80 B rows)
    #pragma unroll
    for (int r = 0; r < 16; r++){
      float rr = av[r]*inv;              // 0 for dead pos -> clean zeros
      rsA[r] += rr;
      int och = (r&3) + 8*(r>>2) + 4*half;
      t2[och*40 + pos] = f2bf(rr*rr);
    }

    // A-frags from LDS tile (same-wave write->read; compiler inserts lgkmcnt).
    // Also accumulate Sum r^2 from the fragments (och l16 / 16+l16, 8 pos each).
    short8v a0 = *(const short8v*)(t2 + l16*40      + quad*8);
    short8v a1 = *(const short8v*)(t2 + (16+l16)*40 + quad*8);
    {
      float p0 = 0.f, p1 = 0.f;
      #pragma unroll
      for (int i = 0; i < 8; i++){
        p0 += bf2f((ushort_t)a0[i]);
        p1 += bf2f((ushort_t)a1[i]);
      }
      r2B0 += p0; r2B1 += p1;
    }

    // hebb: B = x from tile (fp32) or global gather (bf16)
    if (do_hebb){
      if (fp32){
        #pragma unroll
        for (int n = 0; n < 9; n++){
          int kh = n*16 + l16, c = kh/9, ij2 = kh - 9*c, ii = ij2/3, jj = ij2 - 3*ii;
          const float* hp = tw + (c*3 + ii)*TCOLS + jj + quad*8;   // chunk-invariant
          unsigned f[8];
          #pragma unroll
          for (int i = 0; i < 8; i++) f[i] = as_u(hp[i]);
          union{unsigned u[4]; short8v v;} pk;
          pk.u[0] = __builtin_amdgcn_perm(f[1], f[0], 0x07060302u);  // trunc bf16
          pk.u[1] = __builtin_amdgcn_perm(f[3], f[2], 0x07060302u);
          pk.u[2] = __builtin_amdgcn_perm(f[5], f[4], 0x07060302u);
          pk.u[3] = __builtin_amdgcn_perm(f[7], f[6], 0x07060302u);
          hacc[n]   = __builtin_amdgcn_mfma_f32_16x16x32_bf16(a0, pk.v, hacc[n],   0,0,0);
          hacc[9+n] = __builtin_amdgcn_mfma_f32_16x16x32_bf16(a1, pk.v, hacc[9+n], 0,0,0);
        }
      } else {
        int xbase = b*(CIN*HW) + ho*W + wo0;
        #pragma unroll
        for (int n = 0; n < 9; n++){
          int kh = n*16 + l16, c = kh/9, ij2 = kh - 9*c, ii = ij2/3, jj = ij2 - 3*ii;
          int ko = (c*H + ii)*W + jj;
          const ushort_t* xp = (const ushort_t*)xv_ + (size_t)(xbase + ko + quad*8);
          union{ushort_t s[8]; short8v v;} pk;
          if (tail && quad == 3){
            u2a u0 = *(const u2a*)xp, u1 = *(const u2a*)(xp+2), u2 = *(const u2a*)(xp+4);
            pk.s[0]=u0.x; pk.s[1]=u0.y; pk.s[2]=u1.x; pk.s[3]=u1.y;
            pk.s[4]=u2.x; pk.s[5]=u2.y; pk.s[6]=0; pk.s[7]=0;
          } else {
            u2a u0 = *(const u2a*)xp,   u1 = *(const u2a*)(xp+2);
            u2a u2 = *(const u2a*)(xp+4), u3 = *(const u2a*)(xp+6);
            pk.s[0]=u0.x; pk.s[1]=u0.y; pk.s[2]=u1.x; pk.s[3]=u1.y;
            pk.s[4]=u2.x; pk.s[5]=u2.y; pk.s[6]=u3.x; pk.s[7]=u3.y;
          }
          hacc[n]   = __builtin_amdgcn_mfma_f32_16x16x32_bf16(a0, pk.v, hacc[n],   0,0,0);
          hacc[9+n] = __builtin_amdgcn_mfma_f32_16x16x32_bf16(a1, pk.v, hacc[9+n], 0,0,0);
        }
      }
    }
  }

  // reduce Sum r per channel (butterfly within each 32-half)
  #pragma unroll
  for (int r = 0; r < 16; r++){
    float a = rsA[r];
    #pragma unroll
    for (int off = 1; off < 32; off <<= 1)
      a += __shfl_xor(a, off);
    if (pos == 0){                       // lanes 0 and 32
      int och = (r&3) + 8*(r>>2) + 4*half;
      atomicAdd(&red_s[och], a);
    }
  }
  // reduce Sum r^2: lanes sharing l16 are {lane, ^16, ^32, ^48}
  r2B0 += __shfl_xor(r2B0, 16); r2B0 += __shfl_xor(r2B0, 32);
  r2B1 += __shfl_xor(r2B1, 16); r2B1 += __shfl_xor(r2B1, 32);
  if (lane < 16){
    atomicAdd(&red_s[32 + lane],      r2B0);   // och = l16
    atomicAdd(&red_s[32 + 16 + lane], r2B1);   // och = 16+l16
  }
  __syncthreads();   // all waves past chunk loop -> xtile dead, redp safe
  if (tid < 32)      atomicAdd(rsum_g  + tid,      red_s[tid]);
  else if (tid < 64) atomicAdd(r2sum_g + (tid-32), red_s[tid]);

  // cross-wave LDS reduce of hebb acc (C/D: col=l16=khat, row=quad*4+rg=o)
  if (do_hebb){
    for (int wv = 0; wv < 4; wv++){
      if (wave == wv){
        #pragma unroll
        for (int mi = 0; mi < 2; mi++)
          #pragma unroll
          for (int n = 0; n < 9; n++)
            #pragma unroll
            for (int rg = 0; rg < 4; rg++){
              int o  = mi*16 + quad*4 + rg;
              int kh = n*16 + l16;
              if (wv == 0) redp[o*KFEAT + kh]  = hacc[mi*9+n][rg];
              else         redp[o*KFEAT + kh] += hacc[mi*9+n][rg];
            }
      }
      __syncthreads();
    }
    float* myp = partial + (size_t)blockIdx.x*4608;
    for (int i = tid; i < 4608; i += 256) myp[i] = redp[i];
  }
}

// Tree stage: 1016 slabs -> 8 slabs. 144 blocks * 256 = 36864 = 8 grp * 4608 col.
__global__ __launch_bounds__(256) void hebb_red(const float* __restrict__ partial,
                                                float* __restrict__ partial2){
  int t = blockIdx.x*256 + threadIdx.x;
  if (t >= NGRP*4608) return;
  int g = t / 4608, col = t - g*4608;
  const float* p = partial + (size_t)g*SLABS_PER_GRP*4608 + col;
  float s0=0.f, s1=0.f, s2=0.f, s3=0.f;
  int j = 0;
  for (; j + 4 <= SLABS_PER_GRP; j += 4){
    s0 += p[(size_t)(j  )*4608];
    s1 += p[(size_t)(j+1)*4608];
    s2 += p[(size_t)(j+2)*4608];
    s3 += p[(size_t)(j+3)*4608];
  }
  for (; j < SLABS_PER_GRP; j++) s0 += p[(size_t)j*4608];
  partial2[t] = ((s0+s1)+(s2+s3));
}

// Fallback (ws too small for partials): LDS-staged, recomputes softmax
// from y, atomics into WS_ACC (cr pre-scaled by 1/rsum).
template<int FP32>
__global__ __launch_bounds__(256) void hebb_passB_fb(
    const void* __restrict__ xv_, const int* __restrict__ mode,
    const float* __restrict__ ws, const void* __restrict__ ybf_,
    float* __restrict__ acc_g){
  if (*mode != FP32) return;
  __shared__ __align__(16) ushort_t crs[32*128];
  __shared__ __align__(16) ushort_t xs[144*128];
  __shared__ float rsinv_s[32];
  int tid = threadIdx.x;
  if (tid < 32){
    float rs = ws[WS_RSUM + tid];
    rsinv_s[tid] = (rs == 0.f) ? 1.f : (1.f/rs);
  }
  __syncthreads();

  float4v av[18];
  #pragma unroll
  for (int i = 0; i < 18; i++) av[i] = (float4v){0.f,0.f,0.f,0.f};
  int wave = tid >> 6, lane = tid & 63;
  int quad = lane >> 4, l16 = lane & 15;
  int t = tid & 127, kh0 = tid >> 7;

  for (int s = blockIdx.x; s < NROWS*2; s += (int)gridDim.x){
    int row = s >> 1, half = s & 1;
    int b = row / HO, ho = row - b*HO;
    int wo0 = half << 7;
    int tlen = half ? (WO - 128) : 128;
    size_t xoff = (size_t)b*(CIN*HW) + (size_t)ho*W + wo0;
    bool tvalid = t < tlen;

    #pragma unroll
    for (int it = 0; it < 72; it++){
      const int kh = 2*it + kh0;
      const int c = kh/9, ij = kh - 9*c, ii = ij/3, jj = ij - 3*ii;
      size_t gi = xoff + (size_t)(c*H + ii)*W + jj + t;
      ushort_t val;
      if (FP32) val = tvalid ? f2bf(((const float*)xv_)[gi]) : (ushort_t)0;
      else      val = tvalid ? ((const ushort_t*)xv_)[gi]    : (ushort_t)0;
      xs[kh*128 + t] = val;
    }
    if (tid < 128){
      if (tvalid){
        float r[32];
        size_t yb = (size_t)b*(OCH*(size_t)LPOS) + (size_t)ho*WO + wo0 + tid;
        float m = -3.0e38f;
        #pragma unroll
        for (int o = 0; o < 32; o++){
          float v = FP32 ? ((const float*)ybf_)[yb + (size_t)o*LPOS]
                         : bf2f(((const ushort_t*)ybf_)[yb + (size_t)o*LPOS]);
          r[o] = v; m = fmaxf(m, v);
        }
        float ssum = 0.f;
        #pragma unroll
        for (int o = 0; o < 32; o++){ r[o] = __expf(r[o]-m); ssum += r[o]; }
        float inv = 1.f/ssum;
        #pragma unroll
        for (int o = 0; o < 32; o++) r[o] *= inv;
        #pragma unroll
        for (int o = 0; o < 32; o++) crs[o*128 + tid] = f2bf(r[o]*r[o]*rsinv_s[o]);
      } else {
        #pragma unroll
        for (int o = 0; o < 32; o++) crs[o*128 + tid] = 0;
      }
    }
    __syncthreads();

    int t0 = wave*32;
    short8v a0 = *(const short8v*)(crs + l16*128      + t0 + quad*8);
    short8v a1 = *(const short8v*)(crs + (16+l16)*128 + t0 + quad*8);
    #pragma unroll
    for (int n = 0; n < 9; n++){
      short8v bfr = *(const short8v*)(xs + (n*16 + l16)*128 + t0 + quad*8);
      av[n]   = __builtin_amdgcn_mfma_f32_16x16x32_bf16(a0, bfr, av[n],   0,0,0);
      av[9+n] = __builtin_amdgcn_mfma_f32_16x16x32_bf16(a1, bfr, av[9+n], 0,0,0);
    }
    __syncthreads();
  }

  #pragma unroll
  for (int mi = 0; mi < 2; mi++)
    #pragma unroll
    for (int n = 0; n < 9; n++)
      #pragma unroll
      for (int rg = 0; rg < 4; rg++){
        int o  = mi*16 + quad*4 + rg;
        int kh = n*16 + l16;
        atomicAdd(acc_g + o*KFEAT + kh, av[mi*9+n][rg]);
      }
}

__global__ __launch_bounds__(256) void hebb_fin(const ushort_t* __restrict__ w,
    const int* __restrict__ mode, const float* __restrict__ ws,
    const float* __restrict__ partial2, int use_rbuf, void* __restrict__ dout){
  int tid = blockIdx.x*256 + threadIdx.x;
  if (tid >= 4608) return;
  const int fp32 = *mode;
  int o = tid / KFEAT;
  float rs = ws[WS_RSUM + o];
  rs = (rs == 0.f) ? 1.f : rs;
  float base;
  if (use_rbuf){
    float s = 0.f;
    #pragma unroll
    for (int j = 0; j < NGRP; j++)
      s += partial2[(size_t)j*4608 + tid];
    base = s / rs;
  } else {
    base = ws[WS_ACC + tid];   // fallback atomics (already /rsum)
  }
  float crsum = ws[WS_R2 + o] / rs;
  float wv = fp32 ? ((const float*)w)[tid] : bf2f(w[tid]);
  float d = base - crsum * wv;
  if (fp32) ((float*)dout)[(size_t)YELEMS + tid] = d;
  else      ((ushort_t*)dout)[(size_t)YELEMS + tid] = f2bf(d);
}

extern "C" void kernel_launch(void* const* d_in, const int* in_sizes, int n_in,
                              void* d_out, int out_size, void* d_ws, size_t ws_size,
                              hipStream_t stream){
  const void* x    = d_in[0];
  const ushort_t* w = (const ushort_t*)d_in[1];
  const void* bias = d_in[2];
  float* ws   = (float*)d_ws;
  int*   mode = (int*)(ws + WS_MODE);
  float* part = ws + WS_PART;
  float* part2 = ws + WS_PART2;
  int use_rbuf = (ws_size >= WS_NEED) ? 1 : 0;

  hebb_prep<<<1, 256, 0, stream>>>((const ushort_t*)x, w, mode, ws);
  hebb_passAB<<<GRIDA, 256, 0, stream>>>(x, bias, mode, ws,
                                         ws + WS_RSUM, ws + WS_R2, d_out,
                                         part, use_rbuf);
  if (use_rbuf){
    hebb_red<<<144, 256, 0, stream>>>(part, part2);
  } else {
    hebb_passB_fb<0><<<512, 256, 0, stream>>>(x, mode, ws, d_out, ws + WS_ACC);
    hebb_passB_fb<1><<<512, 256, 0, stream>>>(x, mode, ws, d_out, ws + WS_ACC);
  }
  hebb_fin<<<18, 256, 0, stream>>>(w, mode, ws, part2, use_rbuf, d_out);
}

// Round 8
// 299.914 us; speedup vs baseline: 1.2436x; 1.2436x over previous
//
#include <hip/hip_runtime.h>

// HebbianConv2d: y = conv2d(x, w/||w||) + bias ; delta_w = cr @ unfold(x) - (sum cr)*w
// where r = softmax_o(y), cr = r^2 / sum_{b,h,w}(r)
//
// R11 -> R12: REVERT the merged-mode kernel (R11 regressed 105->204 us: both
// loop bodies co-resident wrecks regalloc/scheduling; template form is
// deterministic at 105). Re-do the double-buffer CORRECTLY on the clean R10
// base, fixing R9's three confounds: (a) no mode merge; (b) two STATIC call
// sites (halfA->bufA, halfB->bufB) so LDS addresses stay chunk-invariant
// without unrolling; (c) exact vmcnt ledger: at each wait the newest in-
// flight = 16 y-stores + 7 prefetch loads -> vmcnt(23) retires exactly the
// current chunk's loads, never draining stores (prologue vmcnt(7), last
// half vmcnt(16)). Swizzle kept (FETCH 113->38 MB confirmed).

typedef unsigned short ushort_t;
typedef __attribute__((ext_vector_type(8)))  short  short8v;
typedef __attribute__((ext_vector_type(4)))  float  float4v;
typedef __attribute__((ext_vector_type(16))) float  float16v;

struct __attribute__((packed, aligned(4))) f4a { float x,y,z,w; };
struct __attribute__((packed, aligned(2))) u2a { ushort_t x,y; };

#define BATCH 16
#define CIN   16
#define H     256
#define W     256
#define HW    (H*W)
#define OCH   32
#define HO    254
#define WO    254
#define LPOS  (HO*WO)            // 64516
#define YELEMS (BATCH*OCH*LPOS)  // 33032192
#define KFEAT 144
#define NROWS (BATCH*HO)         // 4064
#define NCHUNK (NROWS*8)         // 32512 chunks of 32 padded positions
#define GRIDA 1016               // fused blocks: 1016*4 waves * 8 chunks = 32512 exact
#define CSTEP (GRIDA*4)          // 4064
#define NSLAB GRIDA              // one partial slab per block
#define NGRP  8
#define SLABS_PER_GRP 127        // 1016/8

#define TCOLS 36                 // x-tile floats per row (48 rows = 16c x 3ii)

// ws layout in floats
#define WS_RSUM 0        // 32
#define WS_R2   32       // 32
#define WS_ACC  64       // 4608: fallback atomic accumulator
#define WS_MODE 4672     // 1 int: 0=bf16 inputs, 1=fp32 inputs
#define WS_WNB  4680     // 4608 ushorts (2304 floats): wnb[ij][c][och] bf16
#define WS_PART 8192     // NSLAB*4608 floats
#define WS_PART2 (8192 + NSLAB*4608)          // NGRP*4608 floats
#define WS_NEED ((size_t)(WS_PART2 + NGRP*4608)*4)   // ~18.9 MB

__device__ __forceinline__ float bf2f(ushort_t u){
  union{unsigned u; float f;} c; c.u = ((unsigned)u) << 16; return c.f;
}
__device__ __forceinline__ ushort_t f2bf(float f){
  union{float f; unsigned u;} c; c.f = f;
  unsigned x = c.u;
  return (ushort_t)((x + 0x7fffu + ((x >> 16) & 1u)) >> 16);   // RNE
}
__device__ __forceinline__ unsigned as_u(float f){
  union{float f; unsigned u;} c; c.f = f; return c.u;
}
__device__ __forceinline__ void gload_lds16(const float* g, void* l){
  __builtin_amdgcn_global_load_lds(
      (const __attribute__((address_space(1))) void*)g,
      (__attribute__((address_space(3))) void*)l, 16, 0, 0);
}

// prep (includes mode detect): bf16 N(0,1): exponent <= 0x81. fp32 storage:
// even ushorts are mantissa halves -> ~45% have exp >= 0x8C. Scan 32 KB.
__global__ __launch_bounds__(256) void hebb_prep(const ushort_t* __restrict__ x,
                                                 const ushort_t* __restrict__ w,
                                                 int* __restrict__ mode,
                                                 float* __restrict__ ws){
  int tid = threadIdx.x;
  int bad = 0;
  for (int i = tid; i < 16384; i += 256){
    unsigned e = ((unsigned)x[i] >> 7) & 0xFFu;
    bad |= (e >= 0x8Cu) ? 1 : 0;
  }
  unsigned long long m = __ballot(bad);
  __shared__ unsigned long long sm[4];
  __shared__ int mode_s;
  int wv = tid >> 6;
  if ((tid & 63) == 0) sm[wv] = m;
  __syncthreads();
  if (tid == 0){
    int md = ((sm[0] | sm[1] | sm[2] | sm[3]) != 0ULL) ? 1 : 0;
    *mode = md; mode_s = md;
  }
  __syncthreads();
  const int fp32 = mode_s;
  const float* wf = (const float*)w;
  __shared__ float inv_s[OCH];
  if (tid < OCH){
    float s = 0.f;
    for (int k = 0; k < KFEAT; k++){
      float v = fp32 ? wf[tid*KFEAT + k] : bf2f(w[tid*KFEAT + k]);
      s += v*v;
    }
    float nrm = sqrtf(s);
    inv_s[tid] = (nrm == 0.f) ? 1.f : (1.f/nrm);
  }
  __syncthreads();
  ushort_t* wnb = (ushort_t*)(ws + WS_WNB);
  for (int i = tid; i < 4608; i += 256){
    // i = (ij*16 + c)*32 + o ; k_full = c*9 + ij
    int o = i & 31, rest = i >> 5;
    int ij = rest >> 4, c = rest & 15;
    int k = c*9 + ij;
    float v = fp32 ? wf[o*KFEAT + k] : bf2f(w[o*KFEAT + k]);
    wnb[i] = f2bf(v * inv_s[o]);
    ws[WS_ACC + i] = 0.f;
  }
  if (tid < 64) ws[WS_RSUM + tid] = 0.f;
}

// Fused: MFMA conv + softmax + reductions + y, then hebb r^2 @ x via per-wave
// LDS transpose of r^2 (C-layout -> 16x16x32 A-frag layout). fp32: double-
// buffered x tile with counted-vmcnt prefetch (static per-buffer call sites).
template<int FP32>
__global__ __launch_bounds__(256, 2) void hebb_passAB(
    const void* __restrict__ xv_, const void* __restrict__ bias_,
    const int* __restrict__ mode, const float* __restrict__ ws,
    float* __restrict__ rsum_g, float* __restrict__ r2sum_g,
    void* __restrict__ yout_, float* __restrict__ partial, int do_hebb){
  if (*mode != FP32) return;
  __shared__ __align__(16) float xtile[4][2][1792];  // 57344 B; redp alias post-loop
  __shared__ __align__(16) ushort_t r2t[4][32*40];   // per-wave r^2 tile, stride 40
  __shared__ float red_s[64];
  float* redp = &xtile[0][0][0];                     // 4608 floats, used after loop
  int tid = threadIdx.x;
  if (tid < 64) red_s[tid] = 0.f;
  __syncthreads();
  int wave = tid >> 6, lane = tid & 63;
  int pos = lane & 31, half = lane >> 5;
  int quad = lane >> 4, l16 = lane & 15;

  // XCD swizzle (T1): default dispatch round-robins bids over 8 XCDs; remap so
  // each XCD owns a contiguous block range -> ho-adjacent rows share its L2.
  int bid = (int)blockIdx.x;
  int swz = (bid & 7)*127 + (bid >> 3);              // bijective, 1016 = 8*127

  // conv A-fragments: wnb[ij][c][och]; lane: m = och = lane&31, k = half*8+i
  const ushort_t* wnb = (const ushort_t*)(ws + WS_WNB);
  short8v wa[9];
  #pragma unroll
  for (int ij = 0; ij < 9; ij++){
    union{ushort_t s[8]; short8v v;} pk;
    #pragma unroll
    for (int i = 0; i < 8; i++)
      pk.s[i] = wnb[(ij*16 + half*8 + i)*32 + pos];
    wa[ij] = pk.v;
  }
  // bias per C-reg row: och_r = (r&3)+8*(r>>2)+4*half
  float bv[16];
  #pragma unroll
  for (int r = 0; r < 16; r++){
    int och = (r&3) + 8*(r>>2) + 4*half;
    bv[r] = FP32 ? ((const float*)bias_)[och] : bf2f(((const ushort_t*)bias_)[och]);
  }
  float rsA[16];
  #pragma unroll
  for (int r = 0; r < 16; r++) rsA[r] = 0.f;
  float r2B0 = 0.f, r2B1 = 0.f;          // Sum r^2 for och=l16 and och=16+l16

  // staging slot map (fp32): slot = i*64+lane -> tile row r=slot/9 (c*3+ii),
  // within-row 16B quarter q=slot%9. 7 instrs x 64 lanes covers 48x36 floats.
  int goff[7], qcol[7];
  #pragma unroll
  for (int i = 0; i < 7; i++){
    int slot = i*64 + lane; slot = (slot > 431) ? 431 : slot;
    int rr = slot/9, q = slot - 9*rr;
    int c = rr/3, ii = rr - 3*c;
    goff[i] = c*HW + ii*W;
    qcol[i] = q*4;
  }

  float4v hacc[18];
  #pragma unroll
  for (int i = 0; i < 18; i++) hacc[i] = (float4v){0.f,0.f,0.f,0.f};

  ushort_t* t2 = r2t[wave];
  const int cc0 = swz*4 + wave;          // wave-uniform; exactly 8 chunks/wave

  if (FP32){
    float* twA = &xtile[wave][0][0];
    float* twB = &xtile[wave][1][0];

    // issue 7 global_load_lds for chunk cc into dst
    auto stage = [&](int cc, float* dst){
      int c2 = __builtin_amdgcn_readfirstlane(cc);
      int row = c2 >> 3, sub = c2 & 7;
      int b = row / HO, ho = row - b*HO, wo0 = sub << 5;
      const float* xb = (const float*)xv_ + (size_t)b*(CIN*HW) + (size_t)ho*W;
      #pragma unroll
      for (int i = 0; i < 7; i++){
        int col = wo0 + qcol[i]; col = (col > 252) ? 252 : col;  // stay in-row
        gload_lds16(xb + goff[i] + col, (char*)dst + i*1024);
      }
    };

    // full per-chunk compute from tile tw (conv+y+softmax+r2t+hebb)
    auto body = [&](int cc, const float* tw){
      int c2 = __builtin_amdgcn_readfirstlane(cc);
      int row = c2 >> 3, sub = c2 & 7;
      int b = row / HO, ho = row - b*HO;
      int wo0 = sub << 5;
      int wo = wo0 + pos;               // 254,255 dead on sub==7

      float16v av;
      #pragma unroll
      for (int r = 0; r < 16; r++) av[r] = bv[r];   // C init = bias

      // conv: operands from tile (chunk-invariant LDS addresses)
      #pragma unroll
      for (int ij = 0; ij < 9; ij++){
        const int ii = ij/3, jj = ij - 3*ii;
        unsigned g[8];
        #pragma unroll
        for (int i2 = 0; i2 < 8; i2++)
          g[i2] = as_u(tw[((half*8 + i2)*3 + ii)*TCOLS + pos + jj]) + 0x8000u;
        union{unsigned u[4]; short8v v;} pk;
        pk.u[0] = __builtin_amdgcn_perm(g[1], g[0], 0x07060302u);  // rnd-half-up
        pk.u[1] = __builtin_amdgcn_perm(g[3], g[2], 0x07060302u);
        pk.u[2] = __builtin_amdgcn_perm(g[5], g[4], 0x07060302u);
        pk.u[3] = __builtin_amdgcn_perm(g[7], g[6], 0x07060302u);
        av = __builtin_amdgcn_mfma_f32_32x32x16_bf16(wa[ij], pk.v, av, 0, 0, 0);
      }

      // y store (C/D: col=lane&31=pos, row=(r&3)+8*(r>>2)+4*half=och)
      int valid = (wo < WO) ? 1 : 0;
      if (valid){
        size_t yb = (size_t)b*(OCH*(size_t)LPOS) + (size_t)(half*4)*LPOS
                  + (size_t)ho*WO + wo;
        #pragma unroll
        for (int r = 0; r < 16; r++){
          size_t yi = yb + (size_t)(((r&3) + 8*(r>>2)))*LPOS;
          ((float*)yout_)[yi] = av[r];
        }
      }

      // softmax over och (16 local + partner half via shfl_xor 32)
      float m = -3.0e38f;
      #pragma unroll
      for (int r = 0; r < 16; r++) m = fmaxf(m, av[r]);
      m = fmaxf(m, __shfl_xor(m, 32));
      float s = 0.f;
      #pragma unroll
      for (int r = 0; r < 16; r++){ float e = __expf(av[r] - m); av[r] = e; s += e; }
      s += __shfl_xor(s, 32);
      float inv = valid ? (1.f/s) : 0.f;

      // r^2 -> per-wave LDS tile [och][pos], stride 40 elems (80 B rows)
      #pragma unroll
      for (int r = 0; r < 16; r++){
        float rr = av[r]*inv;            // 0 for dead pos -> clean zeros
        rsA[r] += rr;
        int och = (r&3) + 8*(r>>2) + 4*half;
        t2[och*40 + pos] = f2bf(rr*rr);
      }

      // A-frags from r2 tile; also accumulate Sum r^2 from the fragments
      short8v a0 = *(const short8v*)(t2 + l16*40      + quad*8);
      short8v a1 = *(const short8v*)(t2 + (16+l16)*40 + quad*8);
      {
        float p0 = 0.f, p1 = 0.f;
        #pragma unroll
        for (int i = 0; i < 8; i++){
          p0 += bf2f((ushort_t)a0[i]);
          p1 += bf2f((ushort_t)a1[i]);
        }
        r2B0 += p0; r2B1 += p1;
      }

      // hebb: B = x from tile
      if (do_hebb){
        #pragma unroll
        for (int n = 0; n < 9; n++){
          int kh = n*16 + l16, c = kh/9, ij2 = kh - 9*c, ii = ij2/3, jj = ij2 - 3*ii;
          const float* hp = tw + (c*3 + ii)*TCOLS + jj + quad*8;   // chunk-invariant
          unsigned f[8];
          #pragma unroll
          for (int i = 0; i < 8; i++) f[i] = as_u(hp[i]);
          union{unsigned u[4]; short8v v;} pk;
          pk.u[0] = __builtin_amdgcn_perm(f[1], f[0], 0x07060302u);  // trunc bf16
          pk.u[1] = __builtin_amdgcn_perm(f[3], f[2], 0x07060302u);
          pk.u[2] = __builtin_amdgcn_perm(f[5], f[4], 0x07060302u);
          pk.u[3] = __builtin_amdgcn_perm(f[7], f[6], 0x07060302u);
          hacc[n]   = __builtin_amdgcn_mfma_f32_16x16x32_bf16(a0, pk.v, hacc[n],   0,0,0);
          hacc[9+n] = __builtin_amdgcn_mfma_f32_16x16x32_bf16(a1, pk.v, hacc[9+n], 0,0,0);
        }
      }
    };

    // prologue: chunk 0 -> bufA
    stage(cc0, twA);
    for (int j = 0; j < 4; j++){
      int cA = cc0 + (2*j)*CSTEP;
      int cB = cA + CSTEP;
      // half A: prefetch cB -> bufB, wait for bufA's loads only
      stage(cB, twB);
      // in-flight (old->new): loadsA(7) [, storesPrev(16)] , loadsB(7)
      if (j == 0) asm volatile("s_waitcnt vmcnt(7)"  ::: "memory");
      else        asm volatile("s_waitcnt vmcnt(23)" ::: "memory");
      body(cA, twA);                     // issues 16 y-stores
      // half B: prefetch next A-chunk, wait for bufB's loads only
      if (j < 3){
        stage(cB + CSTEP, twA);
        // in-flight: loadsB(7), storesA(16), loadsA'(7) -> newest 23 ok
        asm volatile("s_waitcnt vmcnt(23)" ::: "memory");
      } else {
        // in-flight: loadsB(7), storesA(16) -> newest 16 ok
        asm volatile("s_waitcnt vmcnt(16)" ::: "memory");
      }
      body(cB, twB);
    }
  } else {
    // ---- bf16-mode: original scalar-gather loop (no staging) ----
    for (int kk = 0; kk < 8; kk++){
      int cc = __builtin_amdgcn_readfirstlane(cc0 + kk*CSTEP);
      int row = cc >> 3, sub = cc & 7;
      int b = row / HO, ho = row - b*HO;
      int wo0 = sub << 5;
      int wo = wo0 + pos;
      int tail = (sub == 7);

      float16v av;
      #pragma unroll
      for (int r = 0; r < 16; r++) av[r] = bv[r];

      #pragma unroll
      for (int ij = 0; ij < 9; ij++){
        const int ii = ij/3, jj = ij - 3*ii;
        int wcol = wo + jj; wcol = (wcol < 256) ? wcol : 255;   // clamp: no OOB
        size_t a0i = (size_t)b*(CIN*HW) + (size_t)(half*8)*HW + (size_t)(ho+ii)*W + wcol;
        const ushort_t* xp = (const ushort_t*)xv_;
        union{ushort_t s[8]; short8v v;} pk;
        #pragma unroll
        for (int i2 = 0; i2 < 8; i2++)
          pk.s[i2] = xp[a0i + (size_t)i2*HW];
        av = __builtin_amdgcn_mfma_f32_32x32x16_bf16(wa[ij], pk.v, av, 0, 0, 0);
      }

      int valid = (wo < WO) ? 1 : 0;
      if (valid){
        size_t yb = (size_t)b*(OCH*(size_t)LPOS) + (size_t)(half*4)*LPOS
                  + (size_t)ho*WO + wo;
        #pragma unroll
        for (int r = 0; r < 16; r++){
          size_t yi = yb + (size_t)(((r&3) + 8*(r>>2)))*LPOS;
          ((ushort_t*)yout_)[yi] = f2bf(av[r]);
        }
      }

      float m = -3.0e38f;
      #pragma unroll
      for (int r = 0; r < 16; r++) m = fmaxf(m, av[r]);
      m = fmaxf(m, __shfl_xor(m, 32));
      float s = 0.f;
      #pragma unroll
      for (int r = 0; r < 16; r++){ float e = __expf(av[r] - m); av[r] = e; s += e; }
      s += __shfl_xor(s, 32);
      float inv = valid ? (1.f/s) : 0.f;

      #pragma unroll
      for (int r = 0; r < 16; r++){
        float rr = av[r]*inv;
        rsA[r] += rr;
        int och = (r&3) + 8*(r>>2) + 4*half;
        t2[och*40 + pos] = f2bf(rr*rr);
      }

      short8v a0 = *(const short8v*)(t2 + l16*40      + quad*8);
      short8v a1 = *(const short8v*)(t2 + (16+l16)*40 + quad*8);
      {
        float p0 = 0.f, p1 = 0.f;
        #pragma unroll
        for (int i = 0; i < 8; i++){
          p0 += bf2f((ushort_t)a0[i]);
          p1 += bf2f((ushort_t)a1[i]);
        }
        r2B0 += p0; r2B1 += p1;
      }

      if (do_hebb){
        int xbase = b*(CIN*HW) + ho*W + wo0;
        #pragma unroll
        for (int n = 0; n < 9; n++){
          int kh = n*16 + l16, c = kh/9, ij2 = kh - 9*c, ii = ij2/3, jj = ij2 - 3*ii;
          int ko = (c*H + ii)*W + jj;
          const ushort_t* xp = (const ushort_t*)xv_ + (size_t)(xbase + ko + quad*8);
          union{ushort_t s[8]; short8v v;} pk;
          if (tail && quad == 3){
            u2a u0 = *(const u2a*)xp, u1 = *(const u2a*)(xp+2), u2 = *(const u2a*)(xp+4);
            pk.s[0]=u0.x; pk.s[1]=u0.y; pk.s[2]=u1.x; pk.s[3]=u1.y;
            pk.s[4]=u2.x; pk.s[5]=u2.y; pk.s[6]=0; pk.s[7]=0;
          } else {
            u2a u0 = *(const u2a*)xp,   u1 = *(const u2a*)(xp+2);
            u2a u2 = *(const u2a*)(xp+4), u3 = *(const u2a*)(xp+6);
            pk.s[0]=u0.x; pk.s[1]=u0.y; pk.s[2]=u1.x; pk.s[3]=u1.y;
            pk.s[4]=u2.x; pk.s[5]=u2.y; pk.s[6]=u3.x; pk.s[7]=u3.y;
          }
          hacc[n]   = __builtin_amdgcn_mfma_f32_16x16x32_bf16(a0, pk.v, hacc[n],   0,0,0);
          hacc[9+n] = __builtin_amdgcn_mfma_f32_16x16x32_bf16(a1, pk.v, hacc[9+n], 0,0,0);
        }
      }
    }
  }

  // reduce Sum r per channel (butterfly within each 32-half)
  #pragma unroll
  for (int r = 0; r < 16; r++){
    float a = rsA[r];
    #pragma unroll
    for (int off = 1; off < 32; off <<= 1)
      a += __shfl_xor(a, off);
    if (pos == 0){                       // lanes 0 and 32
      int och = (r&3) + 8*(r>>2) + 4*half;
      atomicAdd(&red_s[och], a);
    }
  }
  // reduce Sum r^2: lanes sharing l16 are {lane, ^16, ^32, ^48}
  r2B0 += __shfl_xor(r2B0, 16); r2B0 += __shfl_xor(r2B0, 32);
  r2B1 += __shfl_xor(r2B1, 16); r2B1 += __shfl_xor(r2B1, 32);
  if (lane < 16){
    atomicAdd(&red_s[32 + lane],      r2B0);   // och = l16
    atomicAdd(&red_s[32 + 16 + lane], r2B1);   // och = 16+l16
  }
  __syncthreads();   // all waves past chunk loop -> xtile dead, redp safe
  if (tid < 32)      atomicAdd(rsum_g  + tid,      red_s[tid]);
  else if (tid < 64) atomicAdd(r2sum_g + (tid-32), red_s[tid]);

  // cross-wave LDS reduce of hebb acc (C/D: col=l16=khat, row=quad*4+rg=o)
  if (do_hebb){
    for (int wv = 0; wv < 4; wv++){
      if (wave == wv){
        #pragma unroll
        for (int mi = 0; mi < 2; mi++)
          #pragma unroll
          for (int n = 0; n < 9; n++)
            #pragma unroll
            for (int rg = 0; rg < 4; rg++){
              int o  = mi*16 + quad*4 + rg;
              int kh = n*16 + l16;
              if (wv == 0) redp[o*KFEAT + kh]  = hacc[mi*9+n][rg];
              else         redp[o*KFEAT + kh] += hacc[mi*9+n][rg];
            }
      }
      __syncthreads();
    }
    float* myp = partial + (size_t)blockIdx.x*4608;
    for (int i = tid; i < 4608; i += 256) myp[i] = redp[i];
  }
}

// Tree stage: 1016 slabs -> 8 slabs. 144 blocks * 256 = 36864 = 8 grp * 4608 col.
__global__ __launch_bounds__(256) void hebb_red(const float* __restrict__ partial,
                                                float* __restrict__ partial2){
  int t = blockIdx.x*256 + threadIdx.x;
  if (t >= NGRP*4608) return;
  int g = t / 4608, col = t - g*4608;
  const float* p = partial + (size_t)g*SLABS_PER_GRP*4608 + col;
  float s0=0.f, s1=0.f, s2=0.f, s3=0.f;
  int j = 0;
  for (; j + 4 <= SLABS_PER_GRP; j += 4){
    s0 += p[(size_t)(j  )*4608];
    s1 += p[(size_t)(j+1)*4608];
    s2 += p[(size_t)(j+2)*4608];
    s3 += p[(size_t)(j+3)*4608];
  }
  for (; j < SLABS_PER_GRP; j++) s0 += p[(size_t)j*4608];
  partial2[t] = ((s0+s1)+(s2+s3));
}

// Fallback (ws too small for partials): LDS-staged, recomputes softmax
// from y, atomics into WS_ACC (cr pre-scaled by 1/rsum).
template<int FP32>
__global__ __launch_bounds__(256) void hebb_passB_fb(
    const void* __restrict__ xv_, const int* __restrict__ mode,
    const float* __restrict__ ws, const void* __restrict__ ybf_,
    float* __restrict__ acc_g){
  if (*mode != FP32) return;
  __shared__ __align__(16) ushort_t crs[32*128];
  __shared__ __align__(16) ushort_t xs[144*128];
  __shared__ float rsinv_s[32];
  int tid = threadIdx.x;
  if (tid < 32){
    float rs = ws[WS_RSUM + tid];
    rsinv_s[tid] = (rs == 0.f) ? 1.f : (1.f/rs);
  }
  __syncthreads();

  float4v av[18];
  #pragma unroll
  for (int i = 0; i < 18; i++) av[i] = (float4v){0.f,0.f,0.f,0.f};
  int wave = tid >> 6, lane = tid & 63;
  int quad = lane >> 4, l16 = lane & 15;
  int t = tid & 127, kh0 = tid >> 7;

  for (int s = blockIdx.x; s < NROWS*2; s += (int)gridDim.x){
    int row = s >> 1, half = s & 1;
    int b = row / HO, ho = row - b*HO;
    int wo0 = half << 7;
    int tlen = half ? (WO - 128) : 128;
    size_t xoff = (size_t)b*(CIN*HW) + (size_t)ho*W + wo0;
    bool tvalid = t < tlen;

    #pragma unroll
    for (int it = 0; it < 72; it++){
      const int kh = 2*it + kh0;
      const int c = kh/9, ij = kh - 9*c, ii = ij/3, jj = ij - 3*ii;
      size_t gi = xoff + (size_t)(c*H + ii)*W + jj + t;
      ushort_t val;
      if (FP32) val = tvalid ? f2bf(((const float*)xv_)[gi]) : (ushort_t)0;
      else      val = tvalid ? ((const ushort_t*)xv_)[gi]    : (ushort_t)0;
      xs[kh*128 + t] = val;
    }
    if (tid < 128){
      if (tvalid){
        float r[32];
        size_t yb = (size_t)b*(OCH*(size_t)LPOS) + (size_t)ho*WO + wo0 + tid;
        float m = -3.0e38f;
        #pragma unroll
        for (int o = 0; o < 32; o++){
          float v = FP32 ? ((const float*)ybf_)[yb + (size_t)o*LPOS]
                         : bf2f(((const ushort_t*)ybf_)[yb + (size_t)o*LPOS]);
          r[o] = v; m = fmaxf(m, v);
        }
        float ssum = 0.f;
        #pragma unroll
        for (int o = 0; o < 32; o++){ r[o] = __expf(r[o]-m); ssum += r[o]; }
        float inv = 1.f/ssum;
        #pragma unroll
        for (int o = 0; o < 32; o++) r[o] *= inv;
        #pragma unroll
        for (int o = 0; o < 32; o++) crs[o*128 + tid] = f2bf(r[o]*r[o]*rsinv_s[o]);
      } else {
        #pragma unroll
        for (int o = 0; o < 32; o++) crs[o*128 + tid] = 0;
      }
    }
    __syncthreads();

    int t0 = wave*32;
    short8v a0 = *(const short8v*)(crs + l16*128      + t0 + quad*8);
    short8v a1 = *(const short8v*)(crs + (16+l16)*128 + t0 + quad*8);
    #pragma unroll
    for (int n = 0; n < 9; n++){
      short8v bfr = *(const short8v*)(xs + (n*16 + l16)*128 + t0 + quad*8);
      av[n]   = __builtin_amdgcn_mfma_f32_16x16x32_bf16(a0, bfr, av[n],   0,0,0);
      av[9+n] = __builtin_amdgcn_mfma_f32_16x16x32_bf16(a1, bfr, av[9+n], 0,0,0);
    }
    __syncthreads();
  }

  #pragma unroll
  for (int mi = 0; mi < 2; mi++)
    #pragma unroll
    for (int n = 0; n < 9; n++)
      #pragma unroll
      for (int rg = 0; rg < 4; rg++){
        int o  = mi*16 + quad*4 + rg;
        int kh = n*16 + l16;
        atomicAdd(acc_g + o*KFEAT + kh, av[mi*9+n][rg]);
      }
}

__global__ __launch_bounds__(256) void hebb_fin(const ushort_t* __restrict__ w,
    const int* __restrict__ mode, const float* __restrict__ ws,
    const float* __restrict__ partial2, int use_rbuf, void* __restrict__ dout){
  int tid = blockIdx.x*256 + threadIdx.x;
  if (tid >= 4608) return;
  const int fp32 = *mode;
  int o = tid / KFEAT;
  float rs = ws[WS_RSUM + o];
  rs = (rs == 0.f) ? 1.f : rs;
  float base;
  if (use_rbuf){
    float s = 0.f;
    #pragma unroll
    for (int j = 0; j < NGRP; j++)
      s += partial2[(size_t)j*4608 + tid];
    base = s / rs;
  } else {
    base = ws[WS_ACC + tid];   // fallback atomics (already /rsum)
  }
  float crsum = ws[WS_R2 + o] / rs;
  float wv = fp32 ? ((const float*)w)[tid] : bf2f(w[tid]);
  float d = base - crsum * wv;
  if (fp32) ((float*)dout)[(size_t)YELEMS + tid] = d;
  else      ((ushort_t*)dout)[(size_t)YELEMS + tid] = f2bf(d);
}

extern "C" void kernel_launch(void* const* d_in, const int* in_sizes, int n_in,
                              void* d_out, int out_size, void* d_ws, size_t ws_size,
                              hipStream_t stream){
  const void* x    = d_in[0];
  const ushort_t* w = (const ushort_t*)d_in[1];
  const void* bias = d_in[2];
  float* ws   = (float*)d_ws;
  int*   mode = (int*)(ws + WS_MODE);
  float* part = ws + WS_PART;
  float* part2 = ws + WS_PART2;
  int use_rbuf = (ws_size >= WS_NEED) ? 1 : 0;

  hebb_prep<<<1, 256, 0, stream>>>((const ushort_t*)x, w, mode, ws);
  hebb_passAB<0><<<GRIDA, 256, 0, stream>>>(x, bias, mode, ws,
                                            ws + WS_RSUM, ws + WS_R2, d_out,
                                            part, use_rbuf);
  hebb_passAB<1><<<GRIDA, 256, 0, stream>>>(x, bias, mode, ws,
                                            ws + WS_RSUM, ws + WS_R2, d_out,
                                            part, use_rbuf);
  if (use_rbuf){
    hebb_red<<<144, 256, 0, stream>>>(part, part2);
  } else {
    hebb_passB_fb<0><<<512, 256, 0, stream>>>(x, mode, ws, d_out, ws + WS_ACC);
    hebb_passB_fb<1><<<512, 256, 0, stream>>>(x, mode, ws, d_out, ws + WS_ACC);
  }
  hebb_fin<<<18, 256, 0, stream>>>(w, mode, ws, part2, use_rbuf, d_out);
}

// Round 9
// 281.209 us; speedup vs baseline: 1.3263x; 1.0665x over previous
//
#include <hip/hip_runtime.h>

// HebbianConv2d: y = conv2d(x, w/||w||) + bias ; delta_w = cr @ unfold(x) - (sum cr)*w
// where r = softmax_o(y), cr = r^2 / sum_{b,h,w}(r)
//
// R12 -> R13: REVERT dbuf (falsified: LDS 68KB halves block residency 4->2
// /CU; prefetch < lost TLP; 123 vs 105 us. Third failed pipelining attempt
// -> direction closed). Back to R10 exact (best: 282 total / 105 passAB,
// VGPR=128 at the 4-waves/SIMD boundary). Two independent low-risk adds:
// (1) s_setprio(1) around the hebb MFMA cluster - waves here are barrier-
// free/phase-diverse (the attn-like regime where setprio measured +4-7%,
// not the lockstep-GEMM null); (2) prep norm parallelized (was 32 thr x
// 144 serial loads; now LDS-staged w + 256-thr partials + shfl reduce).

typedef unsigned short ushort_t;
typedef __attribute__((ext_vector_type(8)))  short  short8v;
typedef __attribute__((ext_vector_type(4)))  float  float4v;
typedef __attribute__((ext_vector_type(16))) float  float16v;

struct __attribute__((packed, aligned(4))) f4a { float x,y,z,w; };
struct __attribute__((packed, aligned(2))) u2a { ushort_t x,y; };

#define BATCH 16
#define CIN   16
#define H     256
#define W     256
#define HW    (H*W)
#define OCH   32
#define HO    254
#define WO    254
#define LPOS  (HO*WO)            // 64516
#define YELEMS (BATCH*OCH*LPOS)  // 33032192
#define KFEAT 144
#define NROWS (BATCH*HO)         // 4064
#define NCHUNK (NROWS*8)         // 32512 chunks of 32 padded positions
#define GRIDA 1016               // fused blocks: 1016*4 waves * 8 chunks = 32512 exact
#define NSLAB GRIDA              // one partial slab per block
#define NGRP  8
#define SLABS_PER_GRP 127        // 1016/8

#define TCOLS 36                 // x-tile floats per row (48 rows = 16c x 3ii)

// ws layout in floats
#define WS_RSUM 0        // 32
#define WS_R2   32       // 32
#define WS_ACC  64       // 4608: fallback atomic accumulator
#define WS_MODE 4672     // 1 int: 0=bf16 inputs, 1=fp32 inputs
#define WS_WNB  4680     // 4608 ushorts (2304 floats): wnb[ij][c][och] bf16
#define WS_PART 8192     // NSLAB*4608 floats
#define WS_PART2 (8192 + NSLAB*4608)          // NGRP*4608 floats
#define WS_NEED ((size_t)(WS_PART2 + NGRP*4608)*4)   // ~18.9 MB

__device__ __forceinline__ float bf2f(ushort_t u){
  union{unsigned u; float f;} c; c.u = ((unsigned)u) << 16; return c.f;
}
__device__ __forceinline__ ushort_t f2bf(float f){
  union{float f; unsigned u;} c; c.f = f;
  unsigned x = c.u;
  return (ushort_t)((x + 0x7fffu + ((x >> 16) & 1u)) >> 16);   // RNE
}
__device__ __forceinline__ unsigned as_u(float f){
  union{float f; unsigned u;} c; c.f = f; return c.u;
}
__device__ __forceinline__ void gload_lds16(const float* g, void* l){
  __builtin_amdgcn_global_load_lds(
      (const __attribute__((address_space(1))) void*)g,
      (__attribute__((address_space(3))) void*)l, 16, 0, 0);
}

// prep (includes mode detect): bf16 N(0,1): exponent <= 0x81. fp32 storage:
// even ushorts are mantissa halves -> ~45% have exp >= 0x8C. Scan 32 KB.
// Norm phase: LDS-staged w, 8 threads per och, shfl reduce.
__global__ __launch_bounds__(256) void hebb_prep(const ushort_t* __restrict__ x,
                                                 const ushort_t* __restrict__ w,
                                                 int* __restrict__ mode,
                                                 float* __restrict__ ws){
  int tid = threadIdx.x;
  int bad = 0;
  for (int i = tid; i < 16384; i += 256){
    unsigned e = ((unsigned)x[i] >> 7) & 0xFFu;
    bad |= (e >= 0x8Cu) ? 1 : 0;
  }
  unsigned long long m = __ballot(bad);
  __shared__ unsigned long long sm[4];
  __shared__ int mode_s;
  __shared__ float w_s[4608];
  __shared__ float inv_s[OCH];
  int wv = tid >> 6;
  if ((tid & 63) == 0) sm[wv] = m;
  __syncthreads();
  if (tid == 0){
    int md = ((sm[0] | sm[1] | sm[2] | sm[3]) != 0ULL) ? 1 : 0;
    *mode = md; mode_s = md;
  }
  __syncthreads();
  const int fp32 = mode_s;
  const float* wf = (const float*)w;
  // stage w (converted) into LDS, coalesced
  for (int i = tid; i < 4608; i += 256)
    w_s[i] = fp32 ? wf[i] : bf2f(w[i]);
  __syncthreads();
  // norm: 8 threads per och, 18 elems each, shfl_xor(1,2,4) reduce
  {
    int o = tid >> 3, part = tid & 7;
    float s = 0.f;
    int k0 = part*18;
    for (int k = k0; k < k0+18; k++){ float v = w_s[o*KFEAT + k]; s += v*v; }
    s += __shfl_xor(s, 1); s += __shfl_xor(s, 2); s += __shfl_xor(s, 4);
    if (part == 0){
      float nrm = sqrtf(s);
      inv_s[o] = (nrm == 0.f) ? 1.f : (1.f/nrm);
    }
  }
  __syncthreads();
  ushort_t* wnb = (ushort_t*)(ws + WS_WNB);
  for (int i = tid; i < 4608; i += 256){
    // i = (ij*16 + c)*32 + o ; k_full = c*9 + ij
    int o = i & 31, rest = i >> 5;
    int ij = rest >> 4, c = rest & 15;
    int k = c*9 + ij;
    wnb[i] = f2bf(w_s[o*KFEAT + k] * inv_s[o]);
    ws[WS_ACC + i] = 0.f;
  }
  if (tid < 64) ws[WS_RSUM + tid] = 0.f;
}

// Fused: MFMA conv + softmax + reductions + y, then hebb r^2 @ x via per-wave
// LDS transpose of r^2 (C-layout -> 16x16x32 A-frag layout). x comes from a
// per-wave LDS tile staged once per chunk (fp32 mode). R10 structure.
template<int FP32>
__global__ __launch_bounds__(256, 2) void hebb_passAB(
    const void* __restrict__ xv_, const void* __restrict__ bias_,
    const int* __restrict__ mode, const float* __restrict__ ws,
    float* __restrict__ rsum_g, float* __restrict__ r2sum_g,
    void* __restrict__ yout_, float* __restrict__ partial, int do_hebb){
  if (*mode != FP32) return;
  __shared__ __align__(16) float xtile[4][1792];     // 28672 B; redp alias post-loop
  __shared__ __align__(16) ushort_t r2t[4][32*40];   // per-wave r^2 tile, stride 40
  __shared__ float red_s[64];
  float* redp = &xtile[0][0];                        // 4608 floats, used after loop
  int tid = threadIdx.x;
  if (tid < 64) red_s[tid] = 0.f;
  __syncthreads();
  int wave = tid >> 6, lane = tid & 63;
  int pos = lane & 31, half = lane >> 5;
  int quad = lane >> 4, l16 = lane & 15;

  // XCD swizzle (T1): default dispatch round-robins bids over 8 XCDs; remap so
  // each XCD owns a contiguous block range -> ho-adjacent rows share its L2.
  int bid = (int)blockIdx.x;
  int swz = (bid & 7)*127 + (bid >> 3);              // bijective, 1016 = 8*127

  // conv A-fragments: wnb[ij][c][och]; lane: m = och = lane&31, k = half*8+i
  const ushort_t* wnb = (const ushort_t*)(ws + WS_WNB);
  short8v wa[9];
  #pragma unroll
  for (int ij = 0; ij < 9; ij++){
    union{ushort_t s[8]; short8v v;} pk;
    #pragma unroll
    for (int i = 0; i < 8; i++)
      pk.s[i] = wnb[(ij*16 + half*8 + i)*32 + pos];
    wa[ij] = pk.v;
  }
  // bias per C-reg row: och_r = (r&3)+8*(r>>2)+4*half
  float bv[16];
  #pragma unroll
  for (int r = 0; r < 16; r++){
    int och = (r&3) + 8*(r>>2) + 4*half;
    bv[r] = FP32 ? ((const float*)bias_)[och] : bf2f(((const ushort_t*)bias_)[och]);
  }
  float rsA[16];
  #pragma unroll
  for (int r = 0; r < 16; r++) rsA[r] = 0.f;
  float r2B0 = 0.f, r2B1 = 0.f;          // Sum r^2 for och=l16 and och=16+l16

  // staging slot map (fp32): slot = i*64+lane -> tile row r=slot/9 (c*3+ii),
  // within-row 16B quarter q=slot%9. 7 instrs x 64 lanes covers 48x36 floats.
  int goff[7], qcol[7];
  #pragma unroll
  for (int i = 0; i < 7; i++){
    int slot = i*64 + lane; slot = (slot > 431) ? 431 : slot;
    int rr = slot/9, q = slot - 9*rr;
    int c = rr/3, ii = rr - 3*c;
    goff[i] = c*HW + ii*W;
    qcol[i] = q*4;
  }

  float4v hacc[18];
  #pragma unroll
  for (int i = 0; i < 18; i++) hacc[i] = (float4v){0.f,0.f,0.f,0.f};

  ushort_t* t2 = r2t[wave];
  float* tw = &xtile[wave][0];

  for (int cc0 = swz*4 + wave; cc0 < NCHUNK; cc0 += GRIDA*4){
    int cc = __builtin_amdgcn_readfirstlane(cc0);
    int row = cc >> 3, sub = cc & 7;
    int b = row / HO, ho = row - b*HO;
    int wo0 = sub << 5;
    int wo = wo0 + pos;                 // 254,255 dead on sub==7
    int tail = (sub == 7);

    float16v av;
    #pragma unroll
    for (int r = 0; r < 16; r++) av[r] = bv[r];   // C init = bias

    if (FP32){
      // ---- stage x tile: rows (c*3+ii), cols wo0..wo0+35 (clamped) ----
      const float* xb = (const float*)xv_ + (size_t)b*(CIN*HW) + (size_t)ho*W;
      #pragma unroll
      for (int i = 0; i < 7; i++){
        int col = wo0 + qcol[i]; col = (col > 252) ? 252 : col;  // stay in-row
        gload_lds16(xb + goff[i] + col, (char*)tw + i*1024);
      }
      asm volatile("s_waitcnt vmcnt(0)" ::: "memory");

      // ---- conv: operands from tile (chunk-invariant LDS addresses) ----
      #pragma unroll
      for (int ij = 0; ij < 9; ij++){
        const int ii = ij/3, jj = ij - 3*ii;
        unsigned g[8];
        #pragma unroll
        for (int i2 = 0; i2 < 8; i2++)
          g[i2] = as_u(tw[((half*8 + i2)*3 + ii)*TCOLS + pos + jj]) + 0x8000u;
        union{unsigned u[4]; short8v v;} pk;
        pk.u[0] = __builtin_amdgcn_perm(g[1], g[0], 0x07060302u);  // rnd-half-up
        pk.u[1] = __builtin_amdgcn_perm(g[3], g[2], 0x07060302u);
        pk.u[2] = __builtin_amdgcn_perm(g[5], g[4], 0x07060302u);
        pk.u[3] = __builtin_amdgcn_perm(g[7], g[6], 0x07060302u);
        av = __builtin_amdgcn_mfma_f32_32x32x16_bf16(wa[ij], pk.v, av, 0, 0, 0);
      }
    } else {
      // bf16-mode: original clamped scalar path
      #pragma unroll
      for (int ij = 0; ij < 9; ij++){
        const int ii = ij/3, jj = ij - 3*ii;
        int wcol = wo + jj; wcol = (wcol < 256) ? wcol : 255;   // clamp: no OOB
        size_t a0 = (size_t)b*(CIN*HW) + (size_t)(half*8)*HW + (size_t)(ho+ii)*W + wcol;
        const ushort_t* xp = (const ushort_t*)xv_;
        union{ushort_t s[8]; short8v v;} pk;
        #pragma unroll
        for (int i2 = 0; i2 < 8; i2++)
          pk.s[i2] = xp[a0 + (size_t)i2*HW];
        av = __builtin_amdgcn_mfma_f32_32x32x16_bf16(wa[ij], pk.v, av, 0, 0, 0);
      }
    }

    // y store (C/D: col=lane&31=pos, row=(r&3)+8*(r>>2)+4*half=och)
    int valid = (wo < WO) ? 1 : 0;
    if (valid){
      size_t yb = (size_t)b*(OCH*(size_t)LPOS) + (size_t)(half*4)*LPOS
                + (size_t)ho*WO + wo;
      #pragma unroll
      for (int r = 0; r < 16; r++){
        size_t yi = yb + (size_t)(((r&3) + 8*(r>>2)))*LPOS;
        if (FP32) ((float*)yout_)[yi] = av[r];
        else      ((ushort_t*)yout_)[yi] = f2bf(av[r]);
      }
    }

    // softmax over och (16 local + partner half via shfl_xor 32)
    float m = -3.0e38f;
    #pragma unroll
    for (int r = 0; r < 16; r++) m = fmaxf(m, av[r]);
    m = fmaxf(m, __shfl_xor(m, 32));
    float s = 0.f;
    #pragma unroll
    for (int r = 0; r < 16; r++){ float e = __expf(av[r] - m); av[r] = e; s += e; }
    s += __shfl_xor(s, 32);
    float inv = valid ? (1.f/s) : 0.f;

    // r^2 -> per-wave LDS tile [och][pos], stride 40 elems (80 B rows)
    #pragma unroll
    for (int r = 0; r < 16; r++){
      float rr = av[r]*inv;              // 0 for dead pos -> clean zeros
      rsA[r] += rr;
      int och = (r&3) + 8*(r>>2) + 4*half;
      t2[och*40 + pos] = f2bf(rr*rr);
    }

    // A-frags from LDS tile (same-wave write->read; compiler inserts lgkmcnt).
    // Also accumulate Sum r^2 from the fragments (och l16 / 16+l16, 8 pos each).
    short8v a0 = *(const short8v*)(t2 + l16*40      + quad*8);
    short8v a1 = *(const short8v*)(t2 + (16+l16)*40 + quad*8);
    {
      float p0 = 0.f, p1 = 0.f;
      #pragma unroll
      for (int i = 0; i < 8; i++){
        p0 += bf2f((ushort_t)a0[i]);
        p1 += bf2f((ushort_t)a1[i]);
      }
      r2B0 += p0; r2B1 += p1;
    }

    // hebb: B = x from tile (fp32) or global gather (bf16).
    // setprio(1) over the pure LDS+MFMA cluster (T5; waves are phase-diverse)
    if (do_hebb){
      __builtin_amdgcn_s_setprio(1);
      if (FP32){
        #pragma unroll
        for (int n = 0; n < 9; n++){
          int kh = n*16 + l16, c = kh/9, ij2 = kh - 9*c, ii = ij2/3, jj = ij2 - 3*ii;
          const float* hp = tw + (c*3 + ii)*TCOLS + jj + quad*8;   // chunk-invariant
          unsigned f[8];
          #pragma unroll
          for (int i = 0; i < 8; i++) f[i] = as_u(hp[i]);
          union{unsigned u[4]; short8v v;} pk;
          pk.u[0] = __builtin_amdgcn_perm(f[1], f[0], 0x07060302u);  // trunc bf16
          pk.u[1] = __builtin_amdgcn_perm(f[3], f[2], 0x07060302u);
          pk.u[2] = __builtin_amdgcn_perm(f[5], f[4], 0x07060302u);
          pk.u[3] = __builtin_amdgcn_perm(f[7], f[6], 0x07060302u);
          hacc[n]   = __builtin_amdgcn_mfma_f32_16x16x32_bf16(a0, pk.v, hacc[n],   0,0,0);
          hacc[9+n] = __builtin_amdgcn_mfma_f32_16x16x32_bf16(a1, pk.v, hacc[9+n], 0,0,0);
        }
      } else {
        int xbase = b*(CIN*HW) + ho*W + wo0;
        #pragma unroll
        for (int n = 0; n < 9; n++){
          int kh = n*16 + l16, c = kh/9, ij2 = kh - 9*c, ii = ij2/3, jj = ij2 - 3*ii;
          int ko = (c*H + ii)*W + jj;
          const ushort_t* xp = (const ushort_t*)xv_ + (size_t)(xbase + ko + quad*8);
          union{ushort_t s[8]; short8v v;} pk;
          if (tail && quad == 3){
            u2a u0 = *(const u2a*)xp, u1 = *(const u2a*)(xp+2), u2 = *(const u2a*)(xp+4);
            pk.s[0]=u0.x; pk.s[1]=u0.y; pk.s[2]=u1.x; pk.s[3]=u1.y;
            pk.s[4]=u2.x; pk.s[5]=u2.y; pk.s[6]=0; pk.s[7]=0;
          } else {
            u2a u0 = *(const u2a*)xp,   u1 = *(const u2a*)(xp+2);
            u2a u2 = *(const u2a*)(xp+4), u3 = *(const u2a*)(xp+6);
            pk.s[0]=u0.x; pk.s[1]=u0.y; pk.s[2]=u1.x; pk.s[3]=u1.y;
            pk.s[4]=u2.x; pk.s[5]=u2.y; pk.s[6]=u3.x; pk.s[7]=u3.y;
          }
          hacc[n]   = __builtin_amdgcn_mfma_f32_16x16x32_bf16(a0, pk.v, hacc[n],   0,0,0);
          hacc[9+n] = __builtin_amdgcn_mfma_f32_16x16x32_bf16(a1, pk.v, hacc[9+n], 0,0,0);
        }
      }
      __builtin_amdgcn_s_setprio(0);
    }
  }

  // reduce Sum r per channel (butterfly within each 32-half)
  #pragma unroll
  for (int r = 0; r < 16; r++){
    float a = rsA[r];
    #pragma unroll
    for (int off = 1; off < 32; off <<= 1)
      a += __shfl_xor(a, off);
    if (pos == 0){                       // lanes 0 and 32
      int och = (r&3) + 8*(r>>2) + 4*half;
      atomicAdd(&red_s[och], a);
    }
  }
  // reduce Sum r^2: lanes sharing l16 are {lane, ^16, ^32, ^48}
  r2B0 += __shfl_xor(r2B0, 16); r2B0 += __shfl_xor(r2B0, 32);
  r2B1 += __shfl_xor(r2B1, 16); r2B1 += __shfl_xor(r2B1, 32);
  if (lane < 16){
    atomicAdd(&red_s[32 + lane],      r2B0);   // och = l16
    atomicAdd(&red_s[32 + 16 + lane], r2B1);   // och = 16+l16
  }
  __syncthreads();   // all waves past chunk loop -> xtile dead, redp safe
  if (tid < 32)      atomicAdd(rsum_g  + tid,      red_s[tid]);
  else if (tid < 64) atomicAdd(r2sum_g + (tid-32), red_s[tid]);

  // cross-wave LDS reduce of hebb acc (C/D: col=l16=khat, row=quad*4+rg=o)
  if (do_hebb){
    for (int wv = 0; wv < 4; wv++){
      if (wave == wv){
        #pragma unroll
        for (int mi = 0; mi < 2; mi++)
          #pragma unroll
          for (int n = 0; n < 9; n++)
            #pragma unroll
            for (int rg = 0; rg < 4; rg++){
              int o  = mi*16 + quad*4 + rg;
              int kh = n*16 + l16;
              if (wv == 0) redp[o*KFEAT + kh]  = hacc[mi*9+n][rg];
              else         redp[o*KFEAT + kh] += hacc[mi*9+n][rg];
            }
      }
      __syncthreads();
    }
    float* myp = partial + (size_t)blockIdx.x*4608;
    for (int i = tid; i < 4608; i += 256) myp[i] = redp[i];
  }
}

// Tree stage: 1016 slabs -> 8 slabs. 144 blocks * 256 = 36864 = 8 grp * 4608 col.
__global__ __launch_bounds__(256) void hebb_red(const float* __restrict__ partial,
                                                float* __restrict__ partial2){
  int t = blockIdx.x*256 + threadIdx.x;
  if (t >= NGRP*4608) return;
  int g = t / 4608, col = t - g*4608;
  const float* p = partial + (size_t)g*SLABS_PER_GRP*4608 + col;
  float s0=0.f, s1=0.f, s2=0.f, s3=0.f;
  int j = 0;
  for (; j + 4 <= SLABS_PER_GRP; j += 4){
    s0 += p[(size_t)(j  )*4608];
    s1 += p[(size_t)(j+1)*4608];
    s2 += p[(size_t)(j+2)*4608];
    s3 += p[(size_t)(j+3)*4608];
  }
  for (; j < SLABS_PER_GRP; j++) s0 += p[(size_t)j*4608];
  partial2[t] = ((s0+s1)+(s2+s3));
}

// Fallback (ws too small for partials): LDS-staged, recomputes softmax
// from y, atomics into WS_ACC (cr pre-scaled by 1/rsum).
template<int FP32>
__global__ __launch_bounds__(256) void hebb_passB_fb(
    const void* __restrict__ xv_, const int* __restrict__ mode,
    const float* __restrict__ ws, const void* __restrict__ ybf_,
    float* __restrict__ acc_g){
  if (*mode != FP32) return;
  __shared__ __align__(16) ushort_t crs[32*128];
  __shared__ __align__(16) ushort_t xs[144*128];
  __shared__ float rsinv_s[32];
  int tid = threadIdx.x;
  if (tid < 32){
    float rs = ws[WS_RSUM + tid];
    rsinv_s[tid] = (rs == 0.f) ? 1.f : (1.f/rs);
  }
  __syncthreads();

  float4v av[18];
  #pragma unroll
  for (int i = 0; i < 18; i++) av[i] = (float4v){0.f,0.f,0.f,0.f};
  int wave = tid >> 6, lane = tid & 63;
  int quad = lane >> 4, l16 = lane & 15;
  int t = tid & 127, kh0 = tid >> 7;

  for (int s = blockIdx.x; s < NROWS*2; s += (int)gridDim.x){
    int row = s >> 1, half = s & 1;
    int b = row / HO, ho = row - b*HO;
    int wo0 = half << 7;
    int tlen = half ? (WO - 128) : 128;
    size_t xoff = (size_t)b*(CIN*HW) + (size_t)ho*W + wo0;
    bool tvalid = t < tlen;

    #pragma unroll
    for (int it = 0; it < 72; it++){
      const int kh = 2*it + kh0;
      const int c = kh/9, ij = kh - 9*c, ii = ij/3, jj = ij - 3*ii;
      size_t gi = xoff + (size_t)(c*H + ii)*W + jj + t;
      ushort_t val;
      if (FP32) val = tvalid ? f2bf(((const float*)xv_)[gi]) : (ushort_t)0;
      else      val = tvalid ? ((const ushort_t*)xv_)[gi]    : (ushort_t)0;
      xs[kh*128 + t] = val;
    }
    if (tid < 128){
      if (tvalid){
        float r[32];
        size_t yb = (size_t)b*(OCH*(size_t)LPOS) + (size_t)ho*WO + wo0 + tid;
        float m = -3.0e38f;
        #pragma unroll
        for (int o = 0; o < 32; o++){
          float v = FP32 ? ((const float*)ybf_)[yb + (size_t)o*LPOS]
                         : bf2f(((const ushort_t*)ybf_)[yb + (size_t)o*LPOS]);
          r[o] = v; m = fmaxf(m, v);
        }
        float ssum = 0.f;
        #pragma unroll
        for (int o = 0; o < 32; o++){ r[o] = __expf(r[o]-m); ssum += r[o]; }
        float inv = 1.f/ssum;
        #pragma unroll
        for (int o = 0; o < 32; o++) r[o] *= inv;
        #pragma unroll
        for (int o = 0; o < 32; o++) crs[o*128 + tid] = f2bf(r[o]*r[o]*rsinv_s[o]);
      } else {
        #pragma unroll
        for (int o = 0; o < 32; o++) crs[o*128 + tid] = 0;
      }
    }
    __syncthreads();

    int t0 = wave*32;
    short8v a0 = *(const short8v*)(crs + l16*128      + t0 + quad*8);
    short8v a1 = *(const short8v*)(crs + (16+l16)*128 + t0 + quad*8);
    #pragma unroll
    for (int n = 0; n < 9; n++){
      short8v bfr = *(const short8v*)(xs + (n*16 + l16)*128 + t0 + quad*8);
      av[n]   = __builtin_amdgcn_mfma_f32_16x16x32_bf16(a0, bfr, av[n],   0,0,0);
      av[9+n] = __builtin_amdgcn_mfma_f32_16x16x32_bf16(a1, bfr, av[9+n], 0,0,0);
    }
    __syncthreads();
  }

  #pragma unroll
  for (int mi = 0; mi < 2; mi++)
    #pragma unroll
    for (int n = 0; n < 9; n++)
      #pragma unroll
      for (int rg = 0; rg < 4; rg++){
        int o  = mi*16 + quad*4 + rg;
        int kh = n*16 + l16;
        atomicAdd(acc_g + o*KFEAT + kh, av[mi*9+n][rg]);
      }
}

__global__ __launch_bounds__(256) void hebb_fin(const ushort_t* __restrict__ w,
    const int* __restrict__ mode, const float* __restrict__ ws,
    const float* __restrict__ partial2, int use_rbuf, void* __restrict__ dout){
  int tid = blockIdx.x*256 + threadIdx.x;
  if (tid >= 4608) return;
  const int fp32 = *mode;
  int o = tid / KFEAT;
  float rs = ws[WS_RSUM + o];
  rs = (rs == 0.f) ? 1.f : rs;
  float base;
  if (use_rbuf){
    float s = 0.f;
    #pragma unroll
    for (int j = 0; j < NGRP; j++)
      s += partial2[(size_t)j*4608 + tid];
    base = s / rs;
  } else {
    base = ws[WS_ACC + tid];   // fallback atomics (already /rsum)
  }
  float crsum = ws[WS_R2 + o] / rs;
  float wv = fp32 ? ((const float*)w)[tid] : bf2f(w[tid]);
  float d = base - crsum * wv;
  if (fp32) ((float*)dout)[(size_t)YELEMS + tid] = d;
  else      ((ushort_t*)dout)[(size_t)YELEMS + tid] = f2bf(d);
}

extern "C" void kernel_launch(void* const* d_in, const int* in_sizes, int n_in,
                              void* d_out, int out_size, void* d_ws, size_t ws_size,
                              hipStream_t stream){
  const void* x    = d_in[0];
  const ushort_t* w = (const ushort_t*)d_in[1];
  const void* bias = d_in[2];
  float* ws   = (float*)d_ws;
  int*   mode = (int*)(ws + WS_MODE);
  float* part = ws + WS_PART;
  float* part2 = ws + WS_PART2;
  int use_rbuf = (ws_size >= WS_NEED) ? 1 : 0;

  hebb_prep<<<1, 256, 0, stream>>>((const ushort_t*)x, w, mode, ws);
  hebb_passAB<0><<<GRIDA, 256, 0, stream>>>(x, bias, mode, ws,
                                            ws + WS_RSUM, ws + WS_R2, d_out,
                                            part, use_rbuf);
  hebb_passAB<1><<<GRIDA, 256, 0, stream>>>(x, bias, mode, ws,
                                            ws + WS_RSUM, ws + WS_R2, d_out,
                                            part, use_rbuf);
  if (use_rbuf){
    hebb_red<<<144, 256, 0, stream>>>(part, part2);
  } else {
    hebb_passB_fb<0><<<512, 256, 0, stream>>>(x, mode, ws, d_out, ws + WS_ACC);
    hebb_passB_fb<1><<<512, 256, 0, stream>>>(x, mode, ws, d_out, ws + WS_ACC);
  }
  hebb_fin<<<18, 256, 0, stream>>>(w, mode, ws, part2, use_rbuf, d_out);
}